// Round 13
// baseline (1905.471 us; speedup 1.0000x reference)
//
#include <hip/hip_runtime.h>

// ---------------------------------------------------------------------------
// SanaAttention forward, MI355X (gfx950).
// Numerics (validated r4-r12): np's ReLU(q) signs must be reproduced for BOTH
// the direct attention q AND the ms-branch q (conv of q-slots) -> ALL 16.7M
// q-slot values bit-exact vs np: ONE f32 accumulator, fmaf over k STRICTLY
// ASCENDING (BLAS order). k_qnp4 keeps that per-element recipe.
// Perf history: r8 4x4/64²-tile 134us (54% VALU); r12 8x8/128²-tile 148us
// (11% occupancy - grid-starved, 10.5M B-read conflicts). k_qnp4: 64² tile
// (1024 blocks = 4/CU), m-per-lane + WAVE-UNIFORM j -> B reads are LDS
// broadcasts (no conflicts, offset-immediate addressing); A pitch-20 ~free.
// k/v channels: bf16 MFMA (gemm_kv). conv f64-acc; attn f32; attnB bf16;
// GEMM2 bf16; BN f32.
//
// Memory (per-batch pipeline; ws peak ~136 MB; d_out doubles as scratch):
//   ws[0,48):   qkvT_b f32 -> out2 f32 (64MB) aliases [0,64) after attention
//   ws[48,96):  msT_b f32
//   ws[96,112): xTf f32 | [112,120): xTb bf16
//   ws[120,124): Wkv bf16 | [126,130): Wpack f32 | [130,134): WoutB bf16
//   ws[134,..): BN part (512KB) + stats (8KB)
//   d_out: attnB bf16 (dead before final BN write) -> final NCHW f32
// ---------------------------------------------------------------------------

typedef short bf16x8 __attribute__((ext_vector_type(8)));
typedef float f32x4 __attribute__((ext_vector_type(4)));

__device__ __forceinline__ float bf2f(unsigned short u) {
  union { unsigned int i; float f; } w; w.i = ((unsigned int)u) << 16; return w.f;
}
__device__ __forceinline__ unsigned short f2bf(float f) {
  union { float f; unsigned int i; } w; w.f = f;
  return (unsigned short)((w.i + 0x7fffu + ((w.i >> 16) & 1u)) >> 16);
}

__device__ __forceinline__ void gload16(const void* g, void* l) {
  __builtin_amdgcn_global_load_lds(
      (const __attribute__((address_space(1))) void*)g,
      (__attribute__((address_space(3))) void*)l, 16, 0, 0);
}

static constexpr int BB = 4, CC = 1024, NN = 4096;
static constexpr int C3 = 3 * CC;     // 3072
static constexpr int C2 = 2 * CC;     // 2048
static constexpr int MROWS = BB * NN; // 16384

// --- 1) per-batch transpose: x (C,N) f32 -> xTf (N,C) f32 + xTb bf16 ---------
__global__ __launch_bounds__(256) void k_transpose_both(const float* __restrict__ x,
                                                        float* __restrict__ xTf,
                                                        unsigned short* __restrict__ xTb) {
  __shared__ float tile[32][33];
  const int c0 = blockIdx.y << 5, n0 = blockIdx.x << 5;
  const int tx = threadIdx.x & 31, ty = threadIdx.x >> 5;
#pragma unroll
  for (int i = 0; i < 32; i += 8)
    tile[ty + i][tx] = x[((size_t)(c0 + ty + i)) * NN + n0 + tx];
  __syncthreads();
#pragma unroll
  for (int i = 0; i < 32; i += 8) {
    const float v = tile[tx][ty + i];
    const size_t idx = ((size_t)(n0 + ty + i)) * CC + c0 + tx;
    xTf[idx] = v;
    xTb[idx] = f2bf(v);
  }
}

// --- 2) Wout -> bf16 ---------------------------------------------------------
__global__ void k_cvt(const float* __restrict__ src, unsigned short* __restrict__ dst, int n4) {
  int i = blockIdx.x * 256 + threadIdx.x;
  if (i < n4) {
    float4 v = ((const float4*)src)[i];
    ushort4 o;
    o.x = f2bf(v.x); o.y = f2bf(v.y); o.z = f2bf(v.z); o.w = f2bf(v.w);
    ((ushort4*)dst)[i] = o;
  }
}

// --- 2b) gather q-slot weight rows -> Wpack (1024 x 1024 f32) ----------------
__global__ __launch_bounds__(256) void k_wpack(const float* __restrict__ Wq,
                                               const float* __restrict__ Wk,
                                               const float* __restrict__ Wv,
                                               float* __restrict__ Wpack) {
  const int j = blockIdx.x;
  const int c = 24 * (j >> 3) + (j & 7);
  const float* src = (c < CC) ? (Wq + (size_t)c * CC)
                   : (c < 2 * CC) ? (Wk + (size_t)(c - CC) * CC)
                   : (Wv + (size_t)(c - 2 * CC) * CC);
  const int t = threadIdx.x;
  ((float4*)(Wpack + (size_t)j * CC))[t] = ((const float4*)src)[t];
}

// --- 2c) gather k/v-slot weight rows -> Wkv bf16 (2048 x 1024) ---------------
__global__ __launch_bounds__(256) void k_wkv(const float* __restrict__ Wq,
                                             const float* __restrict__ Wk,
                                             const float* __restrict__ Wv,
                                             unsigned short* __restrict__ Wkv) {
  const int jj = blockIdx.x;
  const int c = 24 * (jj >> 4) + 8 + (jj & 15);
  const float* src = (c < CC) ? (Wq + (size_t)c * CC)
                   : (c < 2 * CC) ? (Wk + (size_t)(c - CC) * CC)
                   : (Wv + (size_t)(c - 2 * CC) * CC);
  const int t = threadIdx.x;
  float4 v = ((const float4*)src)[t];
  ushort4 o;
  o.x = f2bf(v.x); o.y = f2bf(v.y); o.z = f2bf(v.z); o.w = f2bf(v.w);
  ((ushort4*)(Wkv + (size_t)jj * CC))[t] = o;
}

// --- 3a) gemm_kv: qkvT k/v channels = xTb @ Wkv^T (bf16 MFMA, f32 out) -------
__global__ __launch_bounds__(256) void gemm_kv(const unsigned short* __restrict__ A,
                                               const unsigned short* __restrict__ Bmat,
                                               float* __restrict__ qkvT) {
  __shared__ __align__(16) unsigned short lA[128 * 32];
  __shared__ __align__(16) unsigned short lB[128 * 32];
  const int bx = blockIdx.x, by = blockIdx.y;
  const int tid = threadIdx.x, lane = tid & 63, wid = tid >> 6;
  const int wm = wid >> 1, wn = wid & 1;
  const int K = CC;

  const int srow = wid * 32 + (lane >> 2);
  const int skoff = (lane & 3) * 8;
  const unsigned short* Ag = A + (size_t)(bx * 128 + srow) * K + skoff;
  const unsigned short* Bg = Bmat + (size_t)(by * 128 + srow) * K + skoff;
  unsigned short* lAw = &lA[(wid * 32) * 32];
  unsigned short* lBw = &lB[(wid * 32) * 32];

  f32x4 acc[4][4] = {};

  for (int kt = 0; kt < K; kt += 32) {
    gload16(Ag + kt, lAw);
    gload16(Ag + kt + (size_t)16 * K, lAw + 16 * 32);
    gload16(Bg + kt, lBw);
    gload16(Bg + kt + (size_t)16 * K, lBw + 16 * 32);
    __syncthreads();

    const int fr = lane & 15, fkk = (lane >> 4) * 8;
    bf16x8 af[4], bfr[4];
#pragma unroll
    for (int i = 0; i < 4; ++i) {
      af[i]  = *reinterpret_cast<const bf16x8*>(&lA[(wm * 64 + i * 16 + fr) * 32 + fkk]);
      bfr[i] = *reinterpret_cast<const bf16x8*>(&lB[(wn * 64 + i * 16 + fr) * 32 + fkk]);
    }
#pragma unroll
    for (int i = 0; i < 4; ++i)
#pragma unroll
      for (int j = 0; j < 4; ++j)
        acc[i][j] = __builtin_amdgcn_mfma_f32_16x16x32_bf16(af[i], bfr[j], acc[i][j], 0, 0, 0);
    __syncthreads();
  }

  const int fr = lane & 15, fg = lane >> 4;
#pragma unroll
  for (int i = 0; i < 4; ++i) {
    const int row0 = bx * 128 + wm * 64 + i * 16 + fg * 4;
#pragma unroll
    for (int j = 0; j < 4; ++j) {
      const int jj = by * 128 + wn * 64 + j * 16 + fr;     // kv-slot 0..2047
      const int c = 24 * (jj >> 4) + 8 + (jj & 15);        // stacked channel
#pragma unroll
      for (int r = 0; r < 4; ++r)
        qkvT[(size_t)(row0 + r) * C3 + c] = acc[i][j][r];
    }
  }
}

// --- 3b) k_qnp4: np/BLAS-ordered f32 GEMM for ALL q-slot channels ------------
// Bit-match recipe: one f32 acc per output, fmaf over k ASCENDING.
// 64x64 tile (1024 blocks/batch = 4/CU), 256 thr. Lane = m-row (A per-lane,
// pitch 20 ~ 2-way free); wave w owns j in [16w,16w+16) -> B reads are
// wave-uniform LDS broadcasts (no conflicts, offset-immediate addressing).
__global__ __launch_bounds__(256) void k_qnp4(const float* __restrict__ xTf,
                                              const float* __restrict__ Wpack,
                                              float* __restrict__ qkvT) {
  constexpr int PITCH = 20;                 // floats; rows 16B-aligned (80B)
  __shared__ float lA[64 * PITCH];          // [m][k] 64x16
  __shared__ float lB[64 * PITCH];          // [j][k] 64x16
  const int bm = blockIdx.x * 64, bj = blockIdx.y * 64;
  const int t = threadIdx.x;
  const int lane = t & 63, w = t >> 6;
  const int srow = t >> 2, skq = t & 3;     // staging: row, k-quad

  const float* gA = xTf + (size_t)(bm + srow) * CC + skq * 4;
  const float* gB = Wpack + (size_t)(bj + srow) * CC + skq * 4;

  float acc[16];
#pragma unroll
  for (int j = 0; j < 16; ++j) acc[j] = 0.f;

  float4 pa = *(const float4*)(gA);
  float4 pb = *(const float4*)(gB);

  for (int kp = 0; kp < CC; kp += 16) {
    __syncthreads();                        // readers of prev panel done
    *(float4*)&lA[srow * PITCH + skq * 4] = pa;
    *(float4*)&lB[srow * PITCH + skq * 4] = pb;
    __syncthreads();
    if (kp + 16 < CC) {                     // prefetch next panel
      pa = *(const float4*)(gA + kp + 16);
      pb = *(const float4*)(gB + kp + 16);
    }
#pragma unroll
    for (int q = 0; q < 4; ++q) {           // k-quads ascending
      const float4 a = *(const float4*)&lA[lane * PITCH + q * 4];
#pragma unroll
      for (int j = 0; j < 16; ++j) {        // wave-uniform j -> LDS broadcast
        const float4 b = *(const float4*)&lB[(w * 16 + j) * PITCH + q * 4];
        float s = acc[j];
        s = fmaf(a.x, b.x, s);
        s = fmaf(a.y, b.y, s);
        s = fmaf(a.z, b.z, s);
        s = fmaf(a.w, b.w, s);
        acc[j] = s;
      }
    }
  }

  // epilogue: lane's 16 j's = 2 full heads -> 4 contiguous float4 stores
  const int m = bm + lane;
  const int jb = bj + w * 16;
  const int cb0 = 24 * (jb >> 3);           // head 0 channel base
  const int cb1 = 24 * ((jb >> 3) + 1);     // head 1 channel base
  float* d0 = &qkvT[(size_t)m * C3 + cb0];
  float* d1 = &qkvT[(size_t)m * C3 + cb1];
  *(float4*)d0       = make_float4(acc[0],  acc[1],  acc[2],  acc[3]);
  *(float4*)(d0 + 4) = make_float4(acc[4],  acc[5],  acc[6],  acc[7]);
  *(float4*)d1       = make_float4(acc[8],  acc[9],  acc[10], acc[11]);
  *(float4*)(d1 + 4) = make_float4(acc[12], acc[13], acc[14], acc[15]);
}

// --- 3c) gemm_bt plain bf16 (GEMM2), f32 out ---------------------------------
__global__ __launch_bounds__(256) void gemm_bt(const unsigned short* __restrict__ A,
                                               const unsigned short* __restrict__ Bmat,
                                               float* __restrict__ Cout,
                                               int M, int N, int K) {
  __shared__ __align__(16) unsigned short lA[128 * 32];
  __shared__ __align__(16) unsigned short lB[128 * 32];
  const int bx = blockIdx.x, by = blockIdx.y;
  const int tid = threadIdx.x, lane = tid & 63, wid = tid >> 6;
  const int wm = wid >> 1, wn = wid & 1;

  const int srow = wid * 32 + (lane >> 2);
  const int skoff = (lane & 3) * 8;
  const unsigned short* Ag = A + (size_t)(bx * 128 + srow) * K + skoff;
  const unsigned short* Bg = Bmat + (size_t)(by * 128 + srow) * K + skoff;
  unsigned short* lAw = &lA[(wid * 32) * 32];
  unsigned short* lBw = &lB[(wid * 32) * 32];

  f32x4 acc[4][4] = {};

  for (int kt = 0; kt < K; kt += 32) {
    gload16(Ag + kt, lAw);
    gload16(Ag + kt + (size_t)16 * K, lAw + 16 * 32);
    gload16(Bg + kt, lBw);
    gload16(Bg + kt + (size_t)16 * K, lBw + 16 * 32);
    __syncthreads();

    const int fr = lane & 15, fkk = (lane >> 4) * 8;
    bf16x8 af[4], bfr[4];
#pragma unroll
    for (int i = 0; i < 4; ++i) {
      af[i]  = *reinterpret_cast<const bf16x8*>(&lA[(wm * 64 + i * 16 + fr) * 32 + fkk]);
      bfr[i] = *reinterpret_cast<const bf16x8*>(&lB[(wn * 64 + i * 16 + fr) * 32 + fkk]);
    }
#pragma unroll
    for (int i = 0; i < 4; ++i)
#pragma unroll
      for (int j = 0; j < 4; ++j)
        acc[i][j] = __builtin_amdgcn_mfma_f32_16x16x32_bf16(af[i], bfr[j], acc[i][j], 0, 0, 0);
    __syncthreads();
  }

  const int fr = lane & 15, fg = lane >> 4;
#pragma unroll
  for (int i = 0; i < 4; ++i) {
    const int row0 = bx * 128 + wm * 64 + i * 16 + fg * 4;
#pragma unroll
    for (int j = 0; j < 4; ++j) {
      const int col = by * 128 + wn * 64 + j * 16 + fr;
#pragma unroll
      for (int r = 0; r < 4; ++r)
        Cout[(size_t)(row0 + r) * N + col] = acc[i][j][r];
    }
  }
}

// --- 4) multiscale: depthwise 5x5 SAME + grouped 1x1, f64 accumulation -------
__global__ __launch_bounds__(256) void k_conv_ms(const float* __restrict__ qkvT,
                                                 const float* __restrict__ dw_w,
                                                 const float* __restrict__ pw_w,
                                                 float* __restrict__ msT) {
  __shared__ __align__(16) float tin[20][20][8];
  __shared__ float wdw[8][25];
  __shared__ float wpw[8][8];
  const int g = blockIdx.y;
  const int ty0 = (blockIdx.x >> 2) << 4, tx0 = (blockIdx.x & 3) << 4;
  const int tid = threadIdx.x;

  if (tid < 200) wdw[tid / 25][tid % 25] = dw_w[(size_t)(g * 8 + tid / 25) * 25 + tid % 25];
  if (tid < 64) wpw[tid >> 3][tid & 7] = pw_w[(size_t)(g * 8 + (tid >> 3)) * 8 + (tid & 7)];

  for (int p = tid; p < 400; p += 256) {
    const int iy = p / 20, ix = p % 20;
    const int gy = ty0 + iy - 2, gx = tx0 + ix - 2;
    float4 a = make_float4(0, 0, 0, 0), b4 = a;
    if (gy >= 0 && gy < 64 && gx >= 0 && gx < 64) {
      const float* s = &qkvT[((size_t)(gy * 64 + gx)) * C3 + g * 8];
      a = *(const float4*)s;
      b4 = *(const float4*)(s + 4);
    }
    *(float4*)&tin[iy][ix][0] = a;
    *(float4*)&tin[iy][ix][4] = b4;
  }
  __syncthreads();

  const int ty = tid >> 4, tx = tid & 15;
  double acc[8] = {0, 0, 0, 0, 0, 0, 0, 0};
#pragma unroll
  for (int dy = 0; dy < 5; ++dy)
#pragma unroll
    for (int dx = 0; dx < 5; ++dx) {
#pragma unroll
      for (int ci = 0; ci < 8; ++ci)
        acc[ci] += (double)wdw[ci][dy * 5 + dx] * (double)tin[ty + dy][tx + dx][ci];
    }
  float o[8];
#pragma unroll
  for (int co = 0; co < 8; ++co) {
    double s = 0.0;
#pragma unroll
    for (int ci = 0; ci < 8; ++ci) s += (double)wpw[co][ci] * acc[ci];
    o[co] = (float)s;
  }
  const int n = (ty0 + ty) * 64 + tx0 + tx;
  float* d = &msT[((size_t)n) * C3 + g * 8];
  *(float4*)d = make_float4(o[0], o[1], o[2], o[3]);
  *(float4*)(d + 4) = make_float4(o[4], o[5], o[6], o[7]);
}

// --- 5) linear attention per head (per-batch), f32, bf16 ratio out ----------
__global__ __launch_bounds__(256) void k_attn(const float* __restrict__ qkvT,
                                              const float* __restrict__ msT,
                                              unsigned short* __restrict__ attn) {
  const int h = blockIdx.x;
  const float* src = (h < 128) ? qkvT + h * 24 : msT + (h - 128) * 24;
  const int tid = threadIdx.x, lane = tid & 63, wid = tid >> 6;

  float s[72];
#pragma unroll
  for (int i = 0; i < 72; ++i) s[i] = 0.f;

  for (int n = tid; n < NN; n += 256) {
    const float* p = src + (size_t)n * C3;
    float4 k0 = *(const float4*)(p + 8), k1 = *(const float4*)(p + 12);
    float4 v0 = *(const float4*)(p + 16), v1 = *(const float4*)(p + 20);
    float kf[8] = {fmaxf(k0.x, 0.f), fmaxf(k0.y, 0.f), fmaxf(k0.z, 0.f), fmaxf(k0.w, 0.f),
                   fmaxf(k1.x, 0.f), fmaxf(k1.y, 0.f), fmaxf(k1.z, 0.f), fmaxf(k1.w, 0.f)};
    float vf[8] = {v0.x, v0.y, v0.z, v0.w, v1.x, v1.y, v1.z, v1.w};
#pragma unroll
    for (int d = 0; d < 8; ++d)
#pragma unroll
      for (int e = 0; e < 8; ++e) s[d * 8 + e] += vf[d] * kf[e];
#pragma unroll
    for (int e = 0; e < 8; ++e) s[64 + e] += kf[e];
  }

  __shared__ float red[4][72];
  __shared__ float sc[72];
#pragma unroll
  for (int i = 0; i < 72; ++i) {
    float v = s[i];
#pragma unroll
    for (int off = 32; off > 0; off >>= 1) v += __shfl_xor(v, off, 64);
    if (lane == 0) red[wid][i] = v;
  }
  __syncthreads();
  if (tid < 72) sc[tid] = red[0][tid] + red[1][tid] + red[2][tid] + red[3][tid];
  __syncthreads();

  float sl[72];
#pragma unroll
  for (int i = 0; i < 72; ++i) sl[i] = sc[i];

  for (int n = tid; n < NN; n += 256) {
    const float* p = src + (size_t)n * C3;
    float4 q0 = *(const float4*)p, q1 = *(const float4*)(p + 4);
    float qf[8] = {fmaxf(q0.x, 0.f), fmaxf(q0.y, 0.f), fmaxf(q0.z, 0.f), fmaxf(q0.w, 0.f),
                   fmaxf(q1.x, 0.f), fmaxf(q1.y, 0.f), fmaxf(q1.z, 0.f), fmaxf(q1.w, 0.f)};
    float o[9];
#pragma unroll
    for (int d = 0; d < 9; ++d) {
      float t = 0.f;
#pragma unroll
      for (int e = 0; e < 8; ++e) t += sl[d * 8 + e] * qf[e];
      o[d] = t;
    }
    const float inv = 1.f / (o[8] + 1e-15f);
    union { unsigned short u[8]; uint4 v; } res;
#pragma unroll
    for (int d = 0; d < 8; ++d) res.u[d] = f2bf(o[d] * inv);
    *(uint4*)&attn[((size_t)n) * C2 + h * 8] = res.v;
  }
}

// --- 6) BN stats -------------------------------------------------------------
__global__ __launch_bounds__(256) void k_bn_stats(const float* __restrict__ out2,
                                                  float* __restrict__ part) {
  const int ch = blockIdx.x * 256 + threadIdx.x;
  const int r0 = blockIdx.y << 8;
  float s = 0.f, s2 = 0.f;
  for (int i = 0; i < 256; ++i) {
    float v = out2[(size_t)(r0 + i) * CC + ch];
    s += v; s2 += v * v;
  }
  part[((size_t)blockIdx.y * 2 + 0) * CC + ch] = s;
  part[((size_t)blockIdx.y * 2 + 1) * CC + ch] = s2;
}

__global__ __launch_bounds__(256) void k_bn_reduce(const float* __restrict__ part,
                                                   float* __restrict__ stats) {
  const int ch = blockIdx.x * 256 + threadIdx.x;
  float s = 0.f, s2 = 0.f;
  for (int i = 0; i < 64; ++i) {
    s += part[((size_t)i * 2 + 0) * CC + ch];
    s2 += part[((size_t)i * 2 + 1) * CC + ch];
  }
  stats[ch] = s;
  stats[CC + ch] = s2;
}

// --- 7) BN apply + transpose back to NCHW f32 --------------------------------
__global__ __launch_bounds__(256) void k_bn_apply(const float* __restrict__ out2,
                                                  const float* __restrict__ stats,
                                                  const float* __restrict__ gamma,
                                                  const float* __restrict__ beta,
                                                  float* __restrict__ out) {
  __shared__ float tile[32][33];
  const int b = blockIdx.z;
  const int c0 = blockIdx.y << 5, n0 = blockIdx.x << 5;
  const int tx = threadIdx.x & 31, ty = threadIdx.x >> 5;
  const int c = c0 + tx;
  const float mean = stats[c] * (1.f / 16384.f);
  const float var = stats[CC + c] * (1.f / 16384.f) - mean * mean;
  const float scale = gamma[c] * rsqrtf(var + 1e-5f);
  const float shift = beta[c] - mean * scale;
#pragma unroll
  for (int i = 0; i < 32; i += 8)
    tile[ty + i][tx] = out2[((size_t)b * NN + n0 + ty + i) * CC + c] * scale + shift;
  __syncthreads();
#pragma unroll
  for (int i = 0; i < 32; i += 8)
    out[((size_t)b * CC + c0 + ty + i) * NN + n0 + tx] = tile[tx][ty + i];
}

// ---------------------------------------------------------------------------
extern "C" void kernel_launch(void* const* d_in, const int* in_sizes, int n_in,
                              void* d_out, int out_size, void* d_ws, size_t ws_size,
                              hipStream_t stream) {
  const float* x     = (const float*)d_in[0];
  const float* Wq    = (const float*)d_in[1];
  const float* Wk    = (const float*)d_in[2];
  const float* Wv    = (const float*)d_in[3];
  const float* dw_w  = (const float*)d_in[4];
  const float* pw_w  = (const float*)d_in[5];
  const float* Wout  = (const float*)d_in[6];
  const float* gamma = (const float*)d_in[7];
  const float* beta  = (const float*)d_in[8];
  float* out = (float*)d_out;
  (void)ws_size; (void)in_sizes; (void)n_in; (void)out_size;

  char* ws = (char*)d_ws;
  const size_t MB = 1024 * 1024;
  float*          qkvT = (float*)(ws + 0);                   // 48 MB per-batch
  float*          msT  = (float*)(ws + 48 * MB);             // 48 MB per-batch
  float*          xTf  = (float*)(ws + 96 * MB);             // 16 MB per-batch
  unsigned short* xTb  = (unsigned short*)(ws + 112 * MB);   // 8 MB per-batch
  unsigned short* Wkv  = (unsigned short*)(ws + 120 * MB);   // 4 MB
  float*          Wpack= (float*)(ws + 126 * MB);            // 4 MB
  unsigned short* WoutB= (unsigned short*)(ws + 130 * MB);   // 4 MB
  float*          part = (float*)(ws + 134 * MB);            // 512 KB
  float*          stats= (float*)(ws + 135 * MB);            // 8 KB
  float*          out2 = (float*)(ws + 0);                   // 64 MB, aliases dead qkvT/msT
  unsigned short* attnB= (unsigned short*)d_out;             // dead before BN apply

  // weights: Wkv bf16 (2048x1024 gathered k/v rows); Wpack f32; Wout bf16
  k_wkv<<<dim3(C2), 256, 0, stream>>>(Wq, Wk, Wv, Wkv);
  k_wpack<<<dim3(CC), 256, 0, stream>>>(Wq, Wk, Wv, Wpack);
  k_cvt<<<dim3(CC * C2 / 4 / 256), 256, 0, stream>>>(Wout, WoutB, CC * C2 / 4);

  // per-batch: transpose -> kv bf16 GEMM -> np-order q-slots -> conv -> attn
  for (int b = 0; b < BB; ++b) {
    k_transpose_both<<<dim3(NN / 32, CC / 32), 256, 0, stream>>>(x + (size_t)b * CC * NN, xTf, xTb);
    gemm_kv<<<dim3(NN / 128, C2 / 128), 256, 0, stream>>>(xTb, Wkv, qkvT);
    k_qnp4<<<dim3(NN / 64, CC / 64), 256, 0, stream>>>(xTf, Wpack, qkvT);
    k_conv_ms<<<dim3(16, C3 / 8), 256, 0, stream>>>(qkvT, dw_w, pw_w, msT);
    k_attn<<<dim3(256), 256, 0, stream>>>(qkvT, msT, attnB + (size_t)b * NN * C2);
  }

  // GEMM2: out2 = attnB @ Wout^T  (16384 x 1024 x 2048), f32
  gemm_bt<<<dim3(MROWS / 128, CC / 128), 256, 0, stream>>>(attnB, WoutB, out2, MROWS, CC, C2);

  // batch norm + transpose to NCHW
  k_bn_stats<<<dim3(CC / 256, 64), 256, 0, stream>>>(out2, part);
  k_bn_reduce<<<dim3(CC / 256), 256, 0, stream>>>(part, stats);
  k_bn_apply<<<dim3(NN / 32, CC / 32, BB), 256, 0, stream>>>(out2, stats, gamma, beta, out);
}

// Round 14
// 1396.242 us; speedup vs baseline: 1.3647x; 1.3647x over previous
//
#include <hip/hip_runtime.h>

// ---------------------------------------------------------------------------
// SanaAttention forward, MI355X (gfx950).
// Numerics (validated r4-r12): ALL 16.7M q-slot values must be bit-exact vs
// np (ReLU sign flips in q OR ms-q=conv(q) cost ~0.2 absmax): ONE f32
// accumulator per output, fmaf over k STRICTLY ASCENDING. k_qnp5 keeps it.
// Perf ladder for k_qnp (measured): r8 4x4 64²-tile 134us 0-conflict;
// r9 512thr 136 (2.1M cfl); r12 8x8 128² 148 (1/CU grid-starved, 4-way cfl);
// r13 uniform-broadcast 286 (broadcast reads still occupy LDS pipe + pitch-20
// 8-way cfl). Rule: lanes read CONTIGUOUS 16B chunks ([kk][tX*4] pattern).
// k_qnp5: 4x8 blocking (ratio 0.094 LDS-reads/FMA), 64² tile, 128 thr,
// 1024 blocks (4/CU), all reads contiguous -> conflict-free.
// k/v channels: bf16 MFMA (gemm_kv). conv f64-acc; attn f32; attnB bf16;
// GEMM2 bf16; BN f32.
//
// Memory (per-batch pipeline; ws peak ~136 MB; d_out doubles as scratch):
//   ws[0,48):   qkvT_b f32 -> out2 f32 (64MB) aliases [0,64) after attention
//   ws[48,96):  msT_b f32
//   ws[96,112): xTf f32 | [112,120): xTb bf16
//   ws[120,124): Wkv bf16 | [126,130): Wpack f32 | [130,134): WoutB bf16
//   ws[134,..): BN part (512KB) + stats (8KB)
//   d_out: attnB bf16 (dead before final BN write) -> final NCHW f32
// ---------------------------------------------------------------------------

typedef short bf16x8 __attribute__((ext_vector_type(8)));
typedef float f32x4 __attribute__((ext_vector_type(4)));

__device__ __forceinline__ float bf2f(unsigned short u) {
  union { unsigned int i; float f; } w; w.i = ((unsigned int)u) << 16; return w.f;
}
__device__ __forceinline__ unsigned short f2bf(float f) {
  union { float f; unsigned int i; } w; w.f = f;
  return (unsigned short)((w.i + 0x7fffu + ((w.i >> 16) & 1u)) >> 16);
}

__device__ __forceinline__ void gload16(const void* g, void* l) {
  __builtin_amdgcn_global_load_lds(
      (const __attribute__((address_space(1))) void*)g,
      (__attribute__((address_space(3))) void*)l, 16, 0, 0);
}

static constexpr int BB = 4, CC = 1024, NN = 4096;
static constexpr int C3 = 3 * CC;     // 3072
static constexpr int C2 = 2 * CC;     // 2048
static constexpr int MROWS = BB * NN; // 16384

// --- 1) per-batch transpose: x (C,N) f32 -> xTf (N,C) f32 + xTb bf16 ---------
__global__ __launch_bounds__(256) void k_transpose_both(const float* __restrict__ x,
                                                        float* __restrict__ xTf,
                                                        unsigned short* __restrict__ xTb) {
  __shared__ float tile[32][33];
  const int c0 = blockIdx.y << 5, n0 = blockIdx.x << 5;
  const int tx = threadIdx.x & 31, ty = threadIdx.x >> 5;
#pragma unroll
  for (int i = 0; i < 32; i += 8)
    tile[ty + i][tx] = x[((size_t)(c0 + ty + i)) * NN + n0 + tx];
  __syncthreads();
#pragma unroll
  for (int i = 0; i < 32; i += 8) {
    const float v = tile[tx][ty + i];
    const size_t idx = ((size_t)(n0 + ty + i)) * CC + c0 + tx;
    xTf[idx] = v;
    xTb[idx] = f2bf(v);
  }
}

// --- 2) Wout -> bf16 ---------------------------------------------------------
__global__ void k_cvt(const float* __restrict__ src, unsigned short* __restrict__ dst, int n4) {
  int i = blockIdx.x * 256 + threadIdx.x;
  if (i < n4) {
    float4 v = ((const float4*)src)[i];
    ushort4 o;
    o.x = f2bf(v.x); o.y = f2bf(v.y); o.z = f2bf(v.z); o.w = f2bf(v.w);
    ((ushort4*)dst)[i] = o;
  }
}

// --- 2b) gather q-slot weight rows -> Wpack (1024 x 1024 f32) ----------------
__global__ __launch_bounds__(256) void k_wpack(const float* __restrict__ Wq,
                                               const float* __restrict__ Wk,
                                               const float* __restrict__ Wv,
                                               float* __restrict__ Wpack) {
  const int j = blockIdx.x;
  const int c = 24 * (j >> 3) + (j & 7);
  const float* src = (c < CC) ? (Wq + (size_t)c * CC)
                   : (c < 2 * CC) ? (Wk + (size_t)(c - CC) * CC)
                   : (Wv + (size_t)(c - 2 * CC) * CC);
  const int t = threadIdx.x;
  ((float4*)(Wpack + (size_t)j * CC))[t] = ((const float4*)src)[t];
}

// --- 2c) gather k/v-slot weight rows -> Wkv bf16 (2048 x 1024) ---------------
__global__ __launch_bounds__(256) void k_wkv(const float* __restrict__ Wq,
                                             const float* __restrict__ Wk,
                                             const float* __restrict__ Wv,
                                             unsigned short* __restrict__ Wkv) {
  const int jj = blockIdx.x;
  const int c = 24 * (jj >> 4) + 8 + (jj & 15);
  const float* src = (c < CC) ? (Wq + (size_t)c * CC)
                   : (c < 2 * CC) ? (Wk + (size_t)(c - CC) * CC)
                   : (Wv + (size_t)(c - 2 * CC) * CC);
  const int t = threadIdx.x;
  float4 v = ((const float4*)src)[t];
  ushort4 o;
  o.x = f2bf(v.x); o.y = f2bf(v.y); o.z = f2bf(v.z); o.w = f2bf(v.w);
  ((ushort4*)(Wkv + (size_t)jj * CC))[t] = o;
}

// --- 3a) gemm_kv: qkvT k/v channels = xTb @ Wkv^T (bf16 MFMA, f32 out) -------
__global__ __launch_bounds__(256) void gemm_kv(const unsigned short* __restrict__ A,
                                               const unsigned short* __restrict__ Bmat,
                                               float* __restrict__ qkvT) {
  __shared__ __align__(16) unsigned short lA[128 * 32];
  __shared__ __align__(16) unsigned short lB[128 * 32];
  const int bx = blockIdx.x, by = blockIdx.y;
  const int tid = threadIdx.x, lane = tid & 63, wid = tid >> 6;
  const int wm = wid >> 1, wn = wid & 1;
  const int K = CC;

  const int srow = wid * 32 + (lane >> 2);
  const int skoff = (lane & 3) * 8;
  const unsigned short* Ag = A + (size_t)(bx * 128 + srow) * K + skoff;
  const unsigned short* Bg = Bmat + (size_t)(by * 128 + srow) * K + skoff;
  unsigned short* lAw = &lA[(wid * 32) * 32];
  unsigned short* lBw = &lB[(wid * 32) * 32];

  f32x4 acc[4][4] = {};

  for (int kt = 0; kt < K; kt += 32) {
    gload16(Ag + kt, lAw);
    gload16(Ag + kt + (size_t)16 * K, lAw + 16 * 32);
    gload16(Bg + kt, lBw);
    gload16(Bg + kt + (size_t)16 * K, lBw + 16 * 32);
    __syncthreads();

    const int fr = lane & 15, fkk = (lane >> 4) * 8;
    bf16x8 af[4], bfr[4];
#pragma unroll
    for (int i = 0; i < 4; ++i) {
      af[i]  = *reinterpret_cast<const bf16x8*>(&lA[(wm * 64 + i * 16 + fr) * 32 + fkk]);
      bfr[i] = *reinterpret_cast<const bf16x8*>(&lB[(wn * 64 + i * 16 + fr) * 32 + fkk]);
    }
#pragma unroll
    for (int i = 0; i < 4; ++i)
#pragma unroll
      for (int j = 0; j < 4; ++j)
        acc[i][j] = __builtin_amdgcn_mfma_f32_16x16x32_bf16(af[i], bfr[j], acc[i][j], 0, 0, 0);
    __syncthreads();
  }

  const int fr = lane & 15, fg = lane >> 4;
#pragma unroll
  for (int i = 0; i < 4; ++i) {
    const int row0 = bx * 128 + wm * 64 + i * 16 + fg * 4;
#pragma unroll
    for (int j = 0; j < 4; ++j) {
      const int jj = by * 128 + wn * 64 + j * 16 + fr;     // kv-slot 0..2047
      const int c = 24 * (jj >> 4) + 8 + (jj & 15);        // stacked channel
#pragma unroll
      for (int r = 0; r < 4; ++r)
        qkvT[(size_t)(row0 + r) * C3 + c] = acc[i][j][r];
    }
  }
}

// --- 3b) k_qnp5: np/BLAS-ordered f32 GEMM for ALL q-slot channels ------------
// Bit-match recipe: one f32 acc per output, fmaf over k ASCENDING.
// 64x64 tile, 128 thr (1024 blocks = 4/CU, 8 waves/CU). Thread (tm,tj):
// m in {tm*4+i}, j in {tj*4+jj} U {32+tj*4+jj} (4x8). LDS k-major panels
// [16][PITCH=68]; per kk: A read [kk][tm*4] + B reads [kk][tj*4],[kk][32+tj*4]
// -> all contiguous 128B rows across the wave -> conflict-free (r8 pattern).
__global__ __launch_bounds__(128) void k_qnp5(const float* __restrict__ xTf,
                                              const float* __restrict__ Wpack,
                                              float* __restrict__ qkvT) {
  constexpr int PITCH = 68;                  // floats; 272B rows (16B-aligned)
  __shared__ float lA[16 * PITCH];
  __shared__ float lB[16 * PITCH];
  const int bm = blockIdx.x * 64, bj = blockIdx.y * 64;
  const int t = threadIdx.x;                 // 0..127
  const int srow = t >> 1, kh = (t & 1) * 8; // staging: row, k-half
  const int tm = t >> 3, tj = t & 7;         // compute: 16 x 8 thread grid

  const float* gA = xTf + (size_t)(bm + srow) * CC + kh;
  const float* gB = Wpack + (size_t)(bj + srow) * CC + kh;

  float acc[4][8] = {};                      // [i][jj]: jj<4 -> tj*4, else 32+tj*4

  float4 pa0 = *(const float4*)gA;
  float4 pa1 = *(const float4*)(gA + 4);
  float4 pb0 = *(const float4*)gB;
  float4 pb1 = *(const float4*)(gB + 4);

  for (int kp = 0; kp < CC; kp += 16) {
    __syncthreads();                         // readers of prev panel done
    {
      const float a0[4] = {pa0.x, pa0.y, pa0.z, pa0.w};
      const float a1[4] = {pa1.x, pa1.y, pa1.z, pa1.w};
      const float b0[4] = {pb0.x, pb0.y, pb0.z, pb0.w};
      const float b1[4] = {pb1.x, pb1.y, pb1.z, pb1.w};
#pragma unroll
      for (int i = 0; i < 4; ++i) {
        lA[(kh + i) * PITCH + srow]     = a0[i];
        lA[(kh + 4 + i) * PITCH + srow] = a1[i];
        lB[(kh + i) * PITCH + srow]     = b0[i];
        lB[(kh + 4 + i) * PITCH + srow] = b1[i];
      }
    }
    __syncthreads();
    if (kp + 16 < CC) {                      // prefetch next panel
      pa0 = *(const float4*)(gA + kp + 16);
      pa1 = *(const float4*)(gA + kp + 20);
      pb0 = *(const float4*)(gB + kp + 16);
      pb1 = *(const float4*)(gB + kp + 20);
    }
#pragma unroll
    for (int kk = 0; kk < 16; ++kk) {        // k strictly ascending
      const float4 a  = *(const float4*)&lA[kk * PITCH + tm * 4];
      const float4 b0 = *(const float4*)&lB[kk * PITCH + tj * 4];
      const float4 b1 = *(const float4*)&lB[kk * PITCH + 32 + tj * 4];
      const float av[4]  = {a.x, a.y, a.z, a.w};
      const float b0v[4] = {b0.x, b0.y, b0.z, b0.w};
      const float b1v[4] = {b1.x, b1.y, b1.z, b1.w};
#pragma unroll
      for (int i = 0; i < 4; ++i)
#pragma unroll
        for (int jj = 0; jj < 4; ++jj) {
          acc[i][jj]     = fmaf(av[i], b0v[jj], acc[i][jj]);
          acc[i][4 + jj] = fmaf(av[i], b1v[jj], acc[i][4 + jj]);
        }
    }
  }

  // epilogue: j-group tj*4 has (j&7) in {0,4} -> contiguous float4 at
  // channel 24*(j>>3) + (j&7); same for the 32+tj*4 group.
  const int j0 = bj + tj * 4;
  const int j1 = bj + 32 + tj * 4;
  const int c0 = 24 * (j0 >> 3) + (j0 & 7);
  const int c1 = 24 * (j1 >> 3) + (j1 & 7);
#pragma unroll
  for (int i = 0; i < 4; ++i) {
    const int m = bm + tm * 4 + i;
    float* row = &qkvT[(size_t)m * C3];
    *(float4*)(row + c0) = make_float4(acc[i][0], acc[i][1], acc[i][2], acc[i][3]);
    *(float4*)(row + c1) = make_float4(acc[i][4], acc[i][5], acc[i][6], acc[i][7]);
  }
}

// --- 3c) gemm_bt plain bf16 (GEMM2), f32 out ---------------------------------
__global__ __launch_bounds__(256) void gemm_bt(const unsigned short* __restrict__ A,
                                               const unsigned short* __restrict__ Bmat,
                                               float* __restrict__ Cout,
                                               int M, int N, int K) {
  __shared__ __align__(16) unsigned short lA[128 * 32];
  __shared__ __align__(16) unsigned short lB[128 * 32];
  const int bx = blockIdx.x, by = blockIdx.y;
  const int tid = threadIdx.x, lane = tid & 63, wid = tid >> 6;
  const int wm = wid >> 1, wn = wid & 1;

  const int srow = wid * 32 + (lane >> 2);
  const int skoff = (lane & 3) * 8;
  const unsigned short* Ag = A + (size_t)(bx * 128 + srow) * K + skoff;
  const unsigned short* Bg = Bmat + (size_t)(by * 128 + srow) * K + skoff;
  unsigned short* lAw = &lA[(wid * 32) * 32];
  unsigned short* lBw = &lB[(wid * 32) * 32];

  f32x4 acc[4][4] = {};

  for (int kt = 0; kt < K; kt += 32) {
    gload16(Ag + kt, lAw);
    gload16(Ag + kt + (size_t)16 * K, lAw + 16 * 32);
    gload16(Bg + kt, lBw);
    gload16(Bg + kt + (size_t)16 * K, lBw + 16 * 32);
    __syncthreads();

    const int fr = lane & 15, fkk = (lane >> 4) * 8;
    bf16x8 af[4], bfr[4];
#pragma unroll
    for (int i = 0; i < 4; ++i) {
      af[i]  = *reinterpret_cast<const bf16x8*>(&lA[(wm * 64 + i * 16 + fr) * 32 + fkk]);
      bfr[i] = *reinterpret_cast<const bf16x8*>(&lB[(wn * 64 + i * 16 + fr) * 32 + fkk]);
    }
#pragma unroll
    for (int i = 0; i < 4; ++i)
#pragma unroll
      for (int j = 0; j < 4; ++j)
        acc[i][j] = __builtin_amdgcn_mfma_f32_16x16x32_bf16(af[i], bfr[j], acc[i][j], 0, 0, 0);
    __syncthreads();
  }

  const int fr = lane & 15, fg = lane >> 4;
#pragma unroll
  for (int i = 0; i < 4; ++i) {
    const int row0 = bx * 128 + wm * 64 + i * 16 + fg * 4;
#pragma unroll
    for (int j = 0; j < 4; ++j) {
      const int col = by * 128 + wn * 64 + j * 16 + fr;
#pragma unroll
      for (int r = 0; r < 4; ++r)
        Cout[(size_t)(row0 + r) * N + col] = acc[i][j][r];
    }
  }
}

// --- 4) multiscale: depthwise 5x5 SAME + grouped 1x1, f64 accumulation -------
__global__ __launch_bounds__(256) void k_conv_ms(const float* __restrict__ qkvT,
                                                 const float* __restrict__ dw_w,
                                                 const float* __restrict__ pw_w,
                                                 float* __restrict__ msT) {
  __shared__ __align__(16) float tin[20][20][8];
  __shared__ float wdw[8][25];
  __shared__ float wpw[8][8];
  const int g = blockIdx.y;
  const int ty0 = (blockIdx.x >> 2) << 4, tx0 = (blockIdx.x & 3) << 4;
  const int tid = threadIdx.x;

  if (tid < 200) wdw[tid / 25][tid % 25] = dw_w[(size_t)(g * 8 + tid / 25) * 25 + tid % 25];
  if (tid < 64) wpw[tid >> 3][tid & 7] = pw_w[(size_t)(g * 8 + (tid >> 3)) * 8 + (tid & 7)];

  for (int p = tid; p < 400; p += 256) {
    const int iy = p / 20, ix = p % 20;
    const int gy = ty0 + iy - 2, gx = tx0 + ix - 2;
    float4 a = make_float4(0, 0, 0, 0), b4 = a;
    if (gy >= 0 && gy < 64 && gx >= 0 && gx < 64) {
      const float* s = &qkvT[((size_t)(gy * 64 + gx)) * C3 + g * 8];
      a = *(const float4*)s;
      b4 = *(const float4*)(s + 4);
    }
    *(float4*)&tin[iy][ix][0] = a;
    *(float4*)&tin[iy][ix][4] = b4;
  }
  __syncthreads();

  const int ty = tid >> 4, tx = tid & 15;
  double acc[8] = {0, 0, 0, 0, 0, 0, 0, 0};
#pragma unroll
  for (int dy = 0; dy < 5; ++dy)
#pragma unroll
    for (int dx = 0; dx < 5; ++dx) {
#pragma unroll
      for (int ci = 0; ci < 8; ++ci)
        acc[ci] += (double)wdw[ci][dy * 5 + dx] * (double)tin[ty + dy][tx + dx][ci];
    }
  float o[8];
#pragma unroll
  for (int co = 0; co < 8; ++co) {
    double s = 0.0;
#pragma unroll
    for (int ci = 0; ci < 8; ++ci) s += (double)wpw[co][ci] * acc[ci];
    o[co] = (float)s;
  }
  const int n = (ty0 + ty) * 64 + tx0 + tx;
  float* d = &msT[((size_t)n) * C3 + g * 8];
  *(float4*)d = make_float4(o[0], o[1], o[2], o[3]);
  *(float4*)(d + 4) = make_float4(o[4], o[5], o[6], o[7]);
}

// --- 5) linear attention per head (per-batch), f32, bf16 ratio out ----------
__global__ __launch_bounds__(256) void k_attn(const float* __restrict__ qkvT,
                                              const float* __restrict__ msT,
                                              unsigned short* __restrict__ attn) {
  const int h = blockIdx.x;
  const float* src = (h < 128) ? qkvT + h * 24 : msT + (h - 128) * 24;
  const int tid = threadIdx.x, lane = tid & 63, wid = tid >> 6;

  float s[72];
#pragma unroll
  for (int i = 0; i < 72; ++i) s[i] = 0.f;

  for (int n = tid; n < NN; n += 256) {
    const float* p = src + (size_t)n * C3;
    float4 k0 = *(const float4*)(p + 8), k1 = *(const float4*)(p + 12);
    float4 v0 = *(const float4*)(p + 16), v1 = *(const float4*)(p + 20);
    float kf[8] = {fmaxf(k0.x, 0.f), fmaxf(k0.y, 0.f), fmaxf(k0.z, 0.f), fmaxf(k0.w, 0.f),
                   fmaxf(k1.x, 0.f), fmaxf(k1.y, 0.f), fmaxf(k1.z, 0.f), fmaxf(k1.w, 0.f)};
    float vf[8] = {v0.x, v0.y, v0.z, v0.w, v1.x, v1.y, v1.z, v1.w};
#pragma unroll
    for (int d = 0; d < 8; ++d)
#pragma unroll
      for (int e = 0; e < 8; ++e) s[d * 8 + e] += vf[d] * kf[e];
#pragma unroll
    for (int e = 0; e < 8; ++e) s[64 + e] += kf[e];
  }

  __shared__ float red[4][72];
  __shared__ float sc[72];
#pragma unroll
  for (int i = 0; i < 72; ++i) {
    float v = s[i];
#pragma unroll
    for (int off = 32; off > 0; off >>= 1) v += __shfl_xor(v, off, 64);
    if (lane == 0) red[wid][i] = v;
  }
  __syncthreads();
  if (tid < 72) sc[tid] = red[0][tid] + red[1][tid] + red[2][tid] + red[3][tid];
  __syncthreads();

  float sl[72];
#pragma unroll
  for (int i = 0; i < 72; ++i) sl[i] = sc[i];

  for (int n = tid; n < NN; n += 256) {
    const float* p = src + (size_t)n * C3;
    float4 q0 = *(const float4*)p, q1 = *(const float4*)(p + 4);
    float qf[8] = {fmaxf(q0.x, 0.f), fmaxf(q0.y, 0.f), fmaxf(q0.z, 0.f), fmaxf(q0.w, 0.f),
                   fmaxf(q1.x, 0.f), fmaxf(q1.y, 0.f), fmaxf(q1.z, 0.f), fmaxf(q1.w, 0.f)};
    float o[9];
#pragma unroll
    for (int d = 0; d < 9; ++d) {
      float t = 0.f;
#pragma unroll
      for (int e = 0; e < 8; ++e) t += sl[d * 8 + e] * qf[e];
      o[d] = t;
    }
    const float inv = 1.f / (o[8] + 1e-15f);
    union { unsigned short u[8]; uint4 v; } res;
#pragma unroll
    for (int d = 0; d < 8; ++d) res.u[d] = f2bf(o[d] * inv);
    *(uint4*)&attn[((size_t)n) * C2 + h * 8] = res.v;
  }
}

// --- 6) BN stats -------------------------------------------------------------
__global__ __launch_bounds__(256) void k_bn_stats(const float* __restrict__ out2,
                                                  float* __restrict__ part) {
  const int ch = blockIdx.x * 256 + threadIdx.x;
  const int r0 = blockIdx.y << 8;
  float s = 0.f, s2 = 0.f;
  for (int i = 0; i < 256; ++i) {
    float v = out2[(size_t)(r0 + i) * CC + ch];
    s += v; s2 += v * v;
  }
  part[((size_t)blockIdx.y * 2 + 0) * CC + ch] = s;
  part[((size_t)blockIdx.y * 2 + 1) * CC + ch] = s2;
}

__global__ __launch_bounds__(256) void k_bn_reduce(const float* __restrict__ part,
                                                   float* __restrict__ stats) {
  const int ch = blockIdx.x * 256 + threadIdx.x;
  float s = 0.f, s2 = 0.f;
  for (int i = 0; i < 64; ++i) {
    s += part[((size_t)i * 2 + 0) * CC + ch];
    s2 += part[((size_t)i * 2 + 1) * CC + ch];
  }
  stats[ch] = s;
  stats[CC + ch] = s2;
}

// --- 7) BN apply + transpose back to NCHW f32 --------------------------------
__global__ __launch_bounds__(256) void k_bn_apply(const float* __restrict__ out2,
                                                  const float* __restrict__ stats,
                                                  const float* __restrict__ gamma,
                                                  const float* __restrict__ beta,
                                                  float* __restrict__ out) {
  __shared__ float tile[32][33];
  const int b = blockIdx.z;
  const int c0 = blockIdx.y << 5, n0 = blockIdx.x << 5;
  const int tx = threadIdx.x & 31, ty = threadIdx.x >> 5;
  const int c = c0 + tx;
  const float mean = stats[c] * (1.f / 16384.f);
  const float var = stats[CC + c] * (1.f / 16384.f) - mean * mean;
  const float scale = gamma[c] * rsqrtf(var + 1e-5f);
  const float shift = beta[c] - mean * scale;
#pragma unroll
  for (int i = 0; i < 32; i += 8)
    tile[ty + i][tx] = out2[((size_t)b * NN + n0 + ty + i) * CC + c] * scale + shift;
  __syncthreads();
#pragma unroll
  for (int i = 0; i < 32; i += 8)
    out[((size_t)b * CC + c0 + ty + i) * NN + n0 + tx] = tile[tx][ty + i];
}

// ---------------------------------------------------------------------------
extern "C" void kernel_launch(void* const* d_in, const int* in_sizes, int n_in,
                              void* d_out, int out_size, void* d_ws, size_t ws_size,
                              hipStream_t stream) {
  const float* x     = (const float*)d_in[0];
  const float* Wq    = (const float*)d_in[1];
  const float* Wk    = (const float*)d_in[2];
  const float* Wv    = (const float*)d_in[3];
  const float* dw_w  = (const float*)d_in[4];
  const float* pw_w  = (const float*)d_in[5];
  const float* Wout  = (const float*)d_in[6];
  const float* gamma = (const float*)d_in[7];
  const float* beta  = (const float*)d_in[8];
  float* out = (float*)d_out;
  (void)ws_size; (void)in_sizes; (void)n_in; (void)out_size;

  char* ws = (char*)d_ws;
  const size_t MB = 1024 * 1024;
  float*          qkvT = (float*)(ws + 0);                   // 48 MB per-batch
  float*          msT  = (float*)(ws + 48 * MB);             // 48 MB per-batch
  float*          xTf  = (float*)(ws + 96 * MB);             // 16 MB per-batch
  unsigned short* xTb  = (unsigned short*)(ws + 112 * MB);   // 8 MB per-batch
  unsigned short* Wkv  = (unsigned short*)(ws + 120 * MB);   // 4 MB
  float*          Wpack= (float*)(ws + 126 * MB);            // 4 MB
  unsigned short* WoutB= (unsigned short*)(ws + 130 * MB);   // 4 MB
  float*          part = (float*)(ws + 134 * MB);            // 512 KB
  float*          stats= (float*)(ws + 135 * MB);            // 8 KB
  float*          out2 = (float*)(ws + 0);                   // 64 MB, aliases dead qkvT/msT
  unsigned short* attnB= (unsigned short*)d_out;             // dead before BN apply

  // weights: Wkv bf16 (2048x1024 gathered k/v rows); Wpack f32; Wout bf16
  k_wkv<<<dim3(C2), 256, 0, stream>>>(Wq, Wk, Wv, Wkv);
  k_wpack<<<dim3(CC), 256, 0, stream>>>(Wq, Wk, Wv, Wpack);
  k_cvt<<<dim3(CC * C2 / 4 / 256), 256, 0, stream>>>(Wout, WoutB, CC * C2 / 4);

  // per-batch: transpose -> kv bf16 GEMM -> np-order q-slots -> conv -> attn
  for (int b = 0; b < BB; ++b) {
    k_transpose_both<<<dim3(NN / 32, CC / 32), 256, 0, stream>>>(x + (size_t)b * CC * NN, xTf, xTb);
    gemm_kv<<<dim3(NN / 128, C2 / 128), 256, 0, stream>>>(xTb, Wkv, qkvT);
    k_qnp5<<<dim3(NN / 64, CC / 64), 128, 0, stream>>>(xTf, Wpack, qkvT);
    k_conv_ms<<<dim3(16, C3 / 8), 256, 0, stream>>>(qkvT, dw_w, pw_w, msT);
    k_attn<<<dim3(256), 256, 0, stream>>>(qkvT, msT, attnB + (size_t)b * NN * C2);
  }

  // GEMM2: out2 = attnB @ Wout^T  (16384 x 1024 x 2048), f32
  gemm_bt<<<dim3(MROWS / 128, CC / 128), 256, 0, stream>>>(attnB, WoutB, out2, MROWS, CC, C2);

  // batch norm + transpose to NCHW
  k_bn_stats<<<dim3(CC / 256, 64), 256, 0, stream>>>(out2, part);
  k_bn_reduce<<<dim3(CC / 256), 256, 0, stream>>>(part, stats);
  k_bn_apply<<<dim3(NN / 32, CC / 32, BB), 256, 0, stream>>>(out2, stats, gamma, beta, out);
}

// Round 15
// 1296.867 us; speedup vs baseline: 1.4693x; 1.0766x over previous
//
#include <hip/hip_runtime.h>

// ---------------------------------------------------------------------------
// SanaAttention forward, MI355X (gfx950).
// Numerics (validated r4-r14): ALL q-slot values (direct q AND conv inputs
// for ms-q) must be bit-exact vs np: ONE f32 accumulator per output, fmaf
// over k STRICTLY ASCENDING. k_qnp6 keeps that recipe exactly.
// Perf model (r8-r14, 5 data pts): q-GEMM is LDS-BW-bound; need per-thread
// blocking RS/(R+S) >= ~5 AND >=2 blocks/CU. Fix: merge 4 batches into ONE
// 16384-row launch, 8x16/thread, 512 blocks. VALU floor 219us; target ~270.
// Layouts: qAll [16384][1024] (packed q-slots), kvT_b [4096][2048] (packed
// kv-slots), msT_b [4096][3072] (group-packed). conv/attn re-addressed;
// all arithmetic chains identical to the r14-passing kernel.
//
// ws plan (peak ~189MB): qAll [0,64) -> out2 aliases after last attn;
// xTf-all [64,128) dies after k_qnp6 -> msT_b [64,112), kvT_b [112,144);
// xTb-all [144,176); weights [176,188); BN [188,190). attnB in d_out.
// ---------------------------------------------------------------------------

typedef short bf16x8 __attribute__((ext_vector_type(8)));
typedef float f32x4 __attribute__((ext_vector_type(4)));

__device__ __forceinline__ float bf2f(unsigned short u) {
  union { unsigned int i; float f; } w; w.i = ((unsigned int)u) << 16; return w.f;
}
__device__ __forceinline__ unsigned short f2bf(float f) {
  union { float f; unsigned int i; } w; w.f = f;
  return (unsigned short)((w.i + 0x7fffu + ((w.i >> 16) & 1u)) >> 16);
}

__device__ __forceinline__ void gload16(const void* g, void* l) {
  __builtin_amdgcn_global_load_lds(
      (const __attribute__((address_space(1))) void*)g,
      (__attribute__((address_space(3))) void*)l, 16, 0, 0);
}

static constexpr int BB = 4, CC = 1024, NN = 4096;
static constexpr int C3 = 3 * CC;     // 3072
static constexpr int C2 = 2 * CC;     // 2048
static constexpr int MROWS = BB * NN; // 16384

// --- 1) merged transpose: x (B,C,N) f32 -> xTf (B,N,C) f32 + xTb bf16 --------
__global__ __launch_bounds__(256) void k_transpose_both(const float* __restrict__ x,
                                                        float* __restrict__ xTf,
                                                        unsigned short* __restrict__ xTb) {
  __shared__ float tile[32][33];
  const int b = blockIdx.z;
  const int c0 = blockIdx.y << 5, n0 = blockIdx.x << 5;
  const int tx = threadIdx.x & 31, ty = threadIdx.x >> 5;
#pragma unroll
  for (int i = 0; i < 32; i += 8)
    tile[ty + i][tx] = x[((size_t)b * CC + c0 + ty + i) * NN + n0 + tx];
  __syncthreads();
#pragma unroll
  for (int i = 0; i < 32; i += 8) {
    const float v = tile[tx][ty + i];
    const size_t idx = ((size_t)b * NN + n0 + ty + i) * CC + c0 + tx;
    xTf[idx] = v;
    xTb[idx] = f2bf(v);
  }
}

// --- 2) Wout -> bf16 ---------------------------------------------------------
__global__ void k_cvt(const float* __restrict__ src, unsigned short* __restrict__ dst, int n4) {
  int i = blockIdx.x * 256 + threadIdx.x;
  if (i < n4) {
    float4 v = ((const float4*)src)[i];
    ushort4 o;
    o.x = f2bf(v.x); o.y = f2bf(v.y); o.z = f2bf(v.z); o.w = f2bf(v.w);
    ((ushort4*)dst)[i] = o;
  }
}

// --- 2b) gather q-slot weight rows -> Wpack (1024 x 1024 f32) ----------------
__global__ __launch_bounds__(256) void k_wpack(const float* __restrict__ Wq,
                                               const float* __restrict__ Wk,
                                               const float* __restrict__ Wv,
                                               float* __restrict__ Wpack) {
  const int j = blockIdx.x;
  const int c = 24 * (j >> 3) + (j & 7);
  const float* src = (c < CC) ? (Wq + (size_t)c * CC)
                   : (c < 2 * CC) ? (Wk + (size_t)(c - CC) * CC)
                   : (Wv + (size_t)(c - 2 * CC) * CC);
  const int t = threadIdx.x;
  ((float4*)(Wpack + (size_t)j * CC))[t] = ((const float4*)src)[t];
}

// --- 2c) gather k/v-slot weight rows -> Wkv bf16 (2048 x 1024) ---------------
__global__ __launch_bounds__(256) void k_wkv(const float* __restrict__ Wq,
                                             const float* __restrict__ Wk,
                                             const float* __restrict__ Wv,
                                             unsigned short* __restrict__ Wkv) {
  const int jj = blockIdx.x;
  const int c = 24 * (jj >> 4) + 8 + (jj & 15);
  const float* src = (c < CC) ? (Wq + (size_t)c * CC)
                   : (c < 2 * CC) ? (Wk + (size_t)(c - CC) * CC)
                   : (Wv + (size_t)(c - 2 * CC) * CC);
  const int t = threadIdx.x;
  float4 v = ((const float4*)src)[t];
  ushort4 o;
  o.x = f2bf(v.x); o.y = f2bf(v.y); o.z = f2bf(v.z); o.w = f2bf(v.w);
  ((ushort4*)(Wkv + (size_t)jj * CC))[t] = o;
}

// --- 3a) gemm_kv: kvT[n][jj] = xTb_b @ Wkv^T (bf16 MFMA, f32 packed out) -----
__global__ __launch_bounds__(256) void gemm_kv(const unsigned short* __restrict__ A,
                                               const unsigned short* __restrict__ Bmat,
                                               float* __restrict__ kvT) {
  __shared__ __align__(16) unsigned short lA[128 * 32];
  __shared__ __align__(16) unsigned short lB[128 * 32];
  const int bx = blockIdx.x, by = blockIdx.y;
  const int tid = threadIdx.x, lane = tid & 63, wid = tid >> 6;
  const int wm = wid >> 1, wn = wid & 1;
  const int K = CC;

  const int srow = wid * 32 + (lane >> 2);
  const int skoff = (lane & 3) * 8;
  const unsigned short* Ag = A + (size_t)(bx * 128 + srow) * K + skoff;
  const unsigned short* Bg = Bmat + (size_t)(by * 128 + srow) * K + skoff;
  unsigned short* lAw = &lA[(wid * 32) * 32];
  unsigned short* lBw = &lB[(wid * 32) * 32];

  f32x4 acc[4][4] = {};

  for (int kt = 0; kt < K; kt += 32) {
    gload16(Ag + kt, lAw);
    gload16(Ag + kt + (size_t)16 * K, lAw + 16 * 32);
    gload16(Bg + kt, lBw);
    gload16(Bg + kt + (size_t)16 * K, lBw + 16 * 32);
    __syncthreads();

    const int fr = lane & 15, fkk = (lane >> 4) * 8;
    bf16x8 af[4], bfr[4];
#pragma unroll
    for (int i = 0; i < 4; ++i) {
      af[i]  = *reinterpret_cast<const bf16x8*>(&lA[(wm * 64 + i * 16 + fr) * 32 + fkk]);
      bfr[i] = *reinterpret_cast<const bf16x8*>(&lB[(wn * 64 + i * 16 + fr) * 32 + fkk]);
    }
#pragma unroll
    for (int i = 0; i < 4; ++i)
#pragma unroll
      for (int j = 0; j < 4; ++j)
        acc[i][j] = __builtin_amdgcn_mfma_f32_16x16x32_bf16(af[i], bfr[j], acc[i][j], 0, 0, 0);
    __syncthreads();
  }

  const int fr = lane & 15, fg = lane >> 4;
#pragma unroll
  for (int i = 0; i < 4; ++i) {
    const int row0 = bx * 128 + wm * 64 + i * 16 + fg * 4;
#pragma unroll
    for (int j = 0; j < 4; ++j) {
      const int jj = by * 128 + wn * 64 + j * 16 + fr;     // kv-slot 0..2047
#pragma unroll
      for (int r = 0; r < 4; ++r)
        kvT[(size_t)(row0 + r) * C2 + jj] = acc[i][j][r];
    }
  }
}

// --- 3b) k_qnp6: np-ordered f32 GEMM, ALL batches, 8x16/thread ---------------
// qAll[m][j] = fmaf-chain over k ASCENDING, one f32 acc per output.
// Grid (4 bj, 128 bm) = 512 blocks (2/CU), 256 thr (16tm x 16tj).
// LDS: lA [16k][132] (128 m), lB [16k][320] (256 j destaggered j+(j>>4)*4:
// read chunks hit 8 disjoint bank-groups, 2-way only).
__global__ __launch_bounds__(256) void k_qnp6(const float* __restrict__ xTf,
                                              const float* __restrict__ Wpack,
                                              float* __restrict__ qAll) {
  __shared__ float lA[16 * 132];
  __shared__ float lB[16 * 320];
  const int bj = blockIdx.x * 256;           // j-tile (4)
  const int bm = blockIdx.y * 128;           // m-tile (128)
  const int t = threadIdx.x;
  const int tm = t >> 4, tj = t & 15;
  const int arow = t >> 1, akh = (t & 1) * 8;
  const int bcol = t + ((t >> 4) << 2);      // j + (j>>4)*4 destagger

  const float* gA = xTf + (size_t)(bm + arow) * CC + akh;
  const float* gB = Wpack + (size_t)(bj + t) * CC;

  float acc[8][16];
#pragma unroll
  for (int i = 0; i < 8; ++i)
#pragma unroll
    for (int j = 0; j < 16; ++j) acc[i][j] = 0.f;

  float4 pa0 = *(const float4*)gA;
  float4 pa1 = *(const float4*)(gA + 4);
  float4 pb0 = *(const float4*)gB;
  float4 pb1 = *(const float4*)(gB + 4);
  float4 pb2 = *(const float4*)(gB + 8);
  float4 pb3 = *(const float4*)(gB + 12);

  for (int kp = 0; kp < CC; kp += 16) {
    __syncthreads();
#pragma unroll
    for (int i = 0; i < 4; ++i) {
      lA[(akh + i) * 132 + arow]     = pa0[i];
      lA[(akh + 4 + i) * 132 + arow] = pa1[i];
      lB[(i) * 320 + bcol]      = pb0[i];
      lB[(4 + i) * 320 + bcol]  = pb1[i];
      lB[(8 + i) * 320 + bcol]  = pb2[i];
      lB[(12 + i) * 320 + bcol] = pb3[i];
    }
    __syncthreads();
    if (kp + 16 < CC) {
      pa0 = *(const float4*)(gA + kp + 16);
      pa1 = *(const float4*)(gA + kp + 20);
      pb0 = *(const float4*)(gB + kp + 16);
      pb1 = *(const float4*)(gB + kp + 20);
      pb2 = *(const float4*)(gB + kp + 24);
      pb3 = *(const float4*)(gB + kp + 28);
    }
#pragma unroll
    for (int kk = 0; kk < 16; ++kk) {        // k strictly ascending
      const float4 a0 = *(const float4*)&lA[kk * 132 + tm * 8];
      const float4 a1 = *(const float4*)&lA[kk * 132 + tm * 8 + 4];
      const float4 b0 = *(const float4*)&lB[kk * 320 + tj * 20];
      const float4 b1 = *(const float4*)&lB[kk * 320 + tj * 20 + 4];
      const float4 b2 = *(const float4*)&lB[kk * 320 + tj * 20 + 8];
      const float4 b3 = *(const float4*)&lB[kk * 320 + tj * 20 + 12];
      const float av[8]  = {a0.x, a0.y, a0.z, a0.w, a1.x, a1.y, a1.z, a1.w};
      const float bv[16] = {b0.x, b0.y, b0.z, b0.w, b1.x, b1.y, b1.z, b1.w,
                            b2.x, b2.y, b2.z, b2.w, b3.x, b3.y, b3.z, b3.w};
#pragma unroll
      for (int i = 0; i < 8; ++i)
#pragma unroll
        for (int j = 0; j < 16; ++j)
          acc[i][j] = fmaf(av[i], bv[j], acc[i][j]);
    }
  }

#pragma unroll
  for (int i = 0; i < 8; ++i) {
    float* row = qAll + (size_t)(bm + tm * 8 + i) * CC + bj + tj * 16;
    *(float4*)(row)      = make_float4(acc[i][0],  acc[i][1],  acc[i][2],  acc[i][3]);
    *(float4*)(row + 4)  = make_float4(acc[i][4],  acc[i][5],  acc[i][6],  acc[i][7]);
    *(float4*)(row + 8)  = make_float4(acc[i][8],  acc[i][9],  acc[i][10], acc[i][11]);
    *(float4*)(row + 12) = make_float4(acc[i][12], acc[i][13], acc[i][14], acc[i][15]);
  }
}

// --- 3c) gemm_bt plain bf16 (GEMM2), f32 out; grid swapped for A-panel reuse -
__global__ __launch_bounds__(256) void gemm_bt(const unsigned short* __restrict__ A,
                                               const unsigned short* __restrict__ Bmat,
                                               float* __restrict__ Cout,
                                               int M, int N, int K) {
  __shared__ __align__(16) unsigned short lA[128 * 32];
  __shared__ __align__(16) unsigned short lB[128 * 32];
  const int bx = blockIdx.y, by = blockIdx.x;   // x = n-tile (fast) -> A reuse
  const int tid = threadIdx.x, lane = tid & 63, wid = tid >> 6;
  const int wm = wid >> 1, wn = wid & 1;

  const int srow = wid * 32 + (lane >> 2);
  const int skoff = (lane & 3) * 8;
  const unsigned short* Ag = A + (size_t)(bx * 128 + srow) * K + skoff;
  const unsigned short* Bg = Bmat + (size_t)(by * 128 + srow) * K + skoff;
  unsigned short* lAw = &lA[(wid * 32) * 32];
  unsigned short* lBw = &lB[(wid * 32) * 32];

  f32x4 acc[4][4] = {};

  for (int kt = 0; kt < K; kt += 32) {
    gload16(Ag + kt, lAw);
    gload16(Ag + kt + (size_t)16 * K, lAw + 16 * 32);
    gload16(Bg + kt, lBw);
    gload16(Bg + kt + (size_t)16 * K, lBw + 16 * 32);
    __syncthreads();

    const int fr = lane & 15, fkk = (lane >> 4) * 8;
    bf16x8 af[4], bfr[4];
#pragma unroll
    for (int i = 0; i < 4; ++i) {
      af[i]  = *reinterpret_cast<const bf16x8*>(&lA[(wm * 64 + i * 16 + fr) * 32 + fkk]);
      bfr[i] = *reinterpret_cast<const bf16x8*>(&lB[(wn * 64 + i * 16 + fr) * 32 + fkk]);
    }
#pragma unroll
    for (int i = 0; i < 4; ++i)
#pragma unroll
      for (int j = 0; j < 4; ++j)
        acc[i][j] = __builtin_amdgcn_mfma_f32_16x16x32_bf16(af[i], bfr[j], acc[i][j], 0, 0, 0);
    __syncthreads();
  }

  const int fr = lane & 15, fg = lane >> 4;
#pragma unroll
  for (int i = 0; i < 4; ++i) {
    const int row0 = bx * 128 + wm * 64 + i * 16 + fg * 4;
#pragma unroll
    for (int j = 0; j < 4; ++j) {
      const int col = by * 128 + wn * 64 + j * 16 + fr;
#pragma unroll
      for (int r = 0; r < 4; ++r)
        Cout[(size_t)(row0 + r) * N + col] = acc[i][j][r];
    }
  }
}

// --- 4) multiscale conv: inputs from qAll_b (g%3==0) or kvT_b; f64 acc -------
__global__ __launch_bounds__(256) void k_conv_ms(const float* __restrict__ qAll,
                                                 const float* __restrict__ kvT,
                                                 const float* __restrict__ dw_w,
                                                 const float* __restrict__ pw_w,
                                                 float* __restrict__ msT) {
  __shared__ __align__(16) float tin[20][20][8];
  __shared__ float wdw[8][25];
  __shared__ float wpw[8][8];
  const int g = blockIdx.y;
  const int ty0 = (blockIdx.x >> 2) << 4, tx0 = (blockIdx.x & 3) << 4;
  const int tid = threadIdx.x;

  const int tg = g / 3, r = g % 3;
  const float* src;
  int stride;
  if (r == 0)      { src = qAll + tg * 8;        stride = CC; }
  else if (r == 1) { src = kvT + tg * 16;        stride = C2; }
  else             { src = kvT + tg * 16 + 8;    stride = C2; }

  if (tid < 200) wdw[tid / 25][tid % 25] = dw_w[(size_t)(g * 8 + tid / 25) * 25 + tid % 25];
  if (tid < 64) wpw[tid >> 3][tid & 7] = pw_w[(size_t)(g * 8 + (tid >> 3)) * 8 + (tid & 7)];

  for (int p = tid; p < 400; p += 256) {
    const int iy = p / 20, ix = p % 20;
    const int gy = ty0 + iy - 2, gx = tx0 + ix - 2;
    float4 a = make_float4(0, 0, 0, 0), b4 = a;
    if (gy >= 0 && gy < 64 && gx >= 0 && gx < 64) {
      const float* s = src + (size_t)(gy * 64 + gx) * stride;
      a = *(const float4*)s;
      b4 = *(const float4*)(s + 4);
    }
    *(float4*)&tin[iy][ix][0] = a;
    *(float4*)&tin[iy][ix][4] = b4;
  }
  __syncthreads();

  const int ty = tid >> 4, tx = tid & 15;
  double acc[8] = {0, 0, 0, 0, 0, 0, 0, 0};
#pragma unroll
  for (int dy = 0; dy < 5; ++dy)
#pragma unroll
    for (int dx = 0; dx < 5; ++dx) {
#pragma unroll
      for (int ci = 0; ci < 8; ++ci)
        acc[ci] += (double)wdw[ci][dy * 5 + dx] * (double)tin[ty + dy][tx + dx][ci];
    }
  float o[8];
#pragma unroll
  for (int co = 0; co < 8; ++co) {
    double s = 0.0;
#pragma unroll
    for (int ci = 0; ci < 8; ++ci) s += (double)wpw[co][ci] * acc[ci];
    o[co] = (float)s;
  }
  const int n = (ty0 + ty) * 64 + tx0 + tx;
  float* d = &msT[((size_t)n) * C3 + g * 8];
  *(float4*)d = make_float4(o[0], o[1], o[2], o[3]);
  *(float4*)(d + 4) = make_float4(o[4], o[5], o[6], o[7]);
}

// --- 5) linear attention per head (per-batch), f32, bf16 ratio out ----------
__global__ __launch_bounds__(256) void k_attn(const float* __restrict__ qAll,
                                              const float* __restrict__ kvT,
                                              const float* __restrict__ msT,
                                              unsigned short* __restrict__ attn) {
  const int h = blockIdx.x;
  const float *pq, *pk, *pv;
  int sq, sk, sv;
  if (h < 128) {
    pq = qAll + h * 8;  sq = CC;
    pk = kvT + h * 16;  sk = C2;
    pv = pk + 8;        sv = C2;
  } else {
    const float* m0 = msT + (size_t)(h - 128) * 24;
    pq = m0;      sq = C3;
    pk = m0 + 8;  sk = C3;
    pv = m0 + 16; sv = C3;
  }
  const int tid = threadIdx.x, lane = tid & 63, wid = tid >> 6;

  float s[72];
#pragma unroll
  for (int i = 0; i < 72; ++i) s[i] = 0.f;

  for (int n = tid; n < NN; n += 256) {
    float4 k0 = *(const float4*)(pk + (size_t)n * sk);
    float4 k1 = *(const float4*)(pk + (size_t)n * sk + 4);
    float4 v0 = *(const float4*)(pv + (size_t)n * sv);
    float4 v1 = *(const float4*)(pv + (size_t)n * sv + 4);
    float kf[8] = {fmaxf(k0.x, 0.f), fmaxf(k0.y, 0.f), fmaxf(k0.z, 0.f), fmaxf(k0.w, 0.f),
                   fmaxf(k1.x, 0.f), fmaxf(k1.y, 0.f), fmaxf(k1.z, 0.f), fmaxf(k1.w, 0.f)};
    float vf[8] = {v0.x, v0.y, v0.z, v0.w, v1.x, v1.y, v1.z, v1.w};
#pragma unroll
    for (int d = 0; d < 8; ++d)
#pragma unroll
      for (int e = 0; e < 8; ++e) s[d * 8 + e] += vf[d] * kf[e];
#pragma unroll
    for (int e = 0; e < 8; ++e) s[64 + e] += kf[e];
  }

  __shared__ float red[4][72];
  __shared__ float sc[72];
#pragma unroll
  for (int i = 0; i < 72; ++i) {
    float v = s[i];
#pragma unroll
    for (int off = 32; off > 0; off >>= 1) v += __shfl_xor(v, off, 64);
    if (lane == 0) red[wid][i] = v;
  }
  __syncthreads();
  if (tid < 72) sc[tid] = red[0][tid] + red[1][tid] + red[2][tid] + red[3][tid];
  __syncthreads();

  float sl[72];
#pragma unroll
  for (int i = 0; i < 72; ++i) sl[i] = sc[i];

  for (int n = tid; n < NN; n += 256) {
    float4 q0 = *(const float4*)(pq + (size_t)n * sq);
    float4 q1 = *(const float4*)(pq + (size_t)n * sq + 4);
    float qf[8] = {fmaxf(q0.x, 0.f), fmaxf(q0.y, 0.f), fmaxf(q0.z, 0.f), fmaxf(q0.w, 0.f),
                   fmaxf(q1.x, 0.f), fmaxf(q1.y, 0.f), fmaxf(q1.z, 0.f), fmaxf(q1.w, 0.f)};
    float o[9];
#pragma unroll
    for (int d = 0; d < 9; ++d) {
      float t = 0.f;
#pragma unroll
      for (int e = 0; e < 8; ++e) t += sl[d * 8 + e] * qf[e];
      o[d] = t;
    }
    const float inv = 1.f / (o[8] + 1e-15f);
    union { unsigned short u[8]; uint4 v; } res;
#pragma unroll
    for (int d = 0; d < 8; ++d) res.u[d] = f2bf(o[d] * inv);
    *(uint4*)&attn[((size_t)n) * C2 + h * 8] = res.v;
  }
}

// --- 6) BN stats -------------------------------------------------------------
__global__ __launch_bounds__(256) void k_bn_stats(const float* __restrict__ out2,
                                                  float* __restrict__ part) {
  const int ch = blockIdx.x * 256 + threadIdx.x;
  const int r0 = blockIdx.y << 8;
  float s = 0.f, s2 = 0.f;
  for (int i = 0; i < 256; ++i) {
    float v = out2[(size_t)(r0 + i) * CC + ch];
    s += v; s2 += v * v;
  }
  part[((size_t)blockIdx.y * 2 + 0) * CC + ch] = s;
  part[((size_t)blockIdx.y * 2 + 1) * CC + ch] = s2;
}

__global__ __launch_bounds__(256) void k_bn_reduce(const float* __restrict__ part,
                                                   float* __restrict__ stats) {
  const int ch = blockIdx.x * 256 + threadIdx.x;
  float s = 0.f, s2 = 0.f;
  for (int i = 0; i < 64; ++i) {
    s += part[((size_t)i * 2 + 0) * CC + ch];
    s2 += part[((size_t)i * 2 + 1) * CC + ch];
  }
  stats[ch] = s;
  stats[CC + ch] = s2;
}

// --- 7) BN apply + transpose back to NCHW f32 --------------------------------
__global__ __launch_bounds__(256) void k_bn_apply(const float* __restrict__ out2,
                                                  const float* __restrict__ stats,
                                                  const float* __restrict__ gamma,
                                                  const float* __restrict__ beta,
                                                  float* __restrict__ out) {
  __shared__ float tile[32][33];
  const int b = blockIdx.z;
  const int c0 = blockIdx.y << 5, n0 = blockIdx.x << 5;
  const int tx = threadIdx.x & 31, ty = threadIdx.x >> 5;
  const int c = c0 + tx;
  const float mean = stats[c] * (1.f / 16384.f);
  const float var = stats[CC + c] * (1.f / 16384.f) - mean * mean;
  const float scale = gamma[c] * rsqrtf(var + 1e-5f);
  const float shift = beta[c] - mean * scale;
#pragma unroll
  for (int i = 0; i < 32; i += 8)
    tile[ty + i][tx] = out2[((size_t)b * NN + n0 + ty + i) * CC + c] * scale + shift;
  __syncthreads();
#pragma unroll
  for (int i = 0; i < 32; i += 8)
    out[((size_t)b * CC + c0 + ty + i) * NN + n0 + tx] = tile[tx][ty + i];
}

// ---------------------------------------------------------------------------
extern "C" void kernel_launch(void* const* d_in, const int* in_sizes, int n_in,
                              void* d_out, int out_size, void* d_ws, size_t ws_size,
                              hipStream_t stream) {
  const float* x     = (const float*)d_in[0];
  const float* Wq    = (const float*)d_in[1];
  const float* Wk    = (const float*)d_in[2];
  const float* Wv    = (const float*)d_in[3];
  const float* dw_w  = (const float*)d_in[4];
  const float* pw_w  = (const float*)d_in[5];
  const float* Wout  = (const float*)d_in[6];
  const float* gamma = (const float*)d_in[7];
  const float* beta  = (const float*)d_in[8];
  float* out = (float*)d_out;
  (void)ws_size; (void)in_sizes; (void)n_in; (void)out_size;

  char* ws = (char*)d_ws;
  const size_t MB = 1024 * 1024;
  float*          qAll = (float*)(ws + 0);                   // 64 MB (all batches)
  float*          xTf  = (float*)(ws + 64 * MB);             // 64 MB, dies after k_qnp6
  float*          msT  = (float*)(ws + 64 * MB);             // 48 MB, aliases dead xTf
  float*          kvT  = (float*)(ws + 112 * MB);            // 32 MB per-batch
  unsigned short* xTb  = (unsigned short*)(ws + 144 * MB);   // 32 MB (all batches)
  unsigned short* Wkv  = (unsigned short*)(ws + 176 * MB);   // 4 MB
  float*          Wpack= (float*)(ws + 180 * MB);            // 4 MB
  unsigned short* WoutB= (unsigned short*)(ws + 184 * MB);   // 4 MB
  float*          part = (float*)(ws + 188 * MB);            // 512 KB
  float*          stats= (float*)(ws + 189 * MB);            // 8 KB
  float*          out2 = (float*)(ws + 0);                   // 64 MB, aliases dead qAll
  unsigned short* attnB= (unsigned short*)d_out;             // dead before BN apply

  // weights
  k_wkv<<<dim3(C2), 256, 0, stream>>>(Wq, Wk, Wv, Wkv);
  k_wpack<<<dim3(CC), 256, 0, stream>>>(Wq, Wk, Wv, Wpack);
  k_cvt<<<dim3(CC * C2 / 4 / 256), 256, 0, stream>>>(Wout, WoutB, CC * C2 / 4);

  // merged transpose (all 4 batches)
  k_transpose_both<<<dim3(NN / 32, CC / 32, BB), 256, 0, stream>>>(x, xTf, xTb);

  // ONE np-ordered q GEMM over all 16384 rows -> qAll
  k_qnp6<<<dim3(CC / 256, MROWS / 128), 256, 0, stream>>>(xTf, Wpack, qAll);

  // per-batch: kv GEMM -> conv -> attention
  for (int b = 0; b < BB; ++b) {
    const float* qAll_b = qAll + (size_t)b * NN * CC;
    gemm_kv<<<dim3(NN / 128, C2 / 128), 256, 0, stream>>>(
        xTb + (size_t)b * NN * CC, Wkv, kvT);
    k_conv_ms<<<dim3(16, C3 / 8), 256, 0, stream>>>(qAll_b, kvT, dw_w, pw_w, msT);
    k_attn<<<dim3(256), 256, 0, stream>>>(qAll_b, kvT, msT, attnB + (size_t)b * NN * C2);
  }

  // GEMM2: out2 = attnB @ Wout^T  (16384 x 1024 x 2048), f32
  gemm_bt<<<dim3(CC / 128, MROWS / 128), 256, 0, stream>>>(attnB, WoutB, out2, MROWS, CC, C2);

  // batch norm + transpose to NCHW
  k_bn_stats<<<dim3(CC / 256, 64), 256, 0, stream>>>(out2, part);
  k_bn_reduce<<<dim3(CC / 256), 256, 0, stream>>>(part, stats);
  k_bn_apply<<<dim3(NN / 32, CC / 32, BB), 256, 0, stream>>>(out2, stats, gamma, beta, out);
}